// Round 8
// baseline (194.431 us; speedup 1.0000x reference)
//
#include <hip/hip_runtime.h>
#include <hip/hip_bf16.h>
#include <stdint.h>

// MultiHeadSelfAttention (b=2,t=2048,m=1024,h=16,d=64), bf16 MFMA pipeline.
//  - reshape head-split => head h = contiguous 131072-elem slab of the per-batch
//    (2048x1024) projection; the [2048][64] view of the slab is token-ordered.
//  - constant-angle RoPE on q,k cancels exactly in q.k^T => skipped.
//  - K and V stored in a PERMUTED kv order kv' = (n>>6)*128 + (t&127); softmax/PV
//    are permutation-invariant when K and V share the ordering => coalesced VT write.
//  - Q pre-scaled by 0.125*log2(e) so attn softmax runs natively in exp2 domain.
//  - attn consumes K'[kv][d] and VT[d][kv'] fragments DIRECTLY from global (L2):
//    every MFMA fragment is a contiguous 16B load, so no LDS staging, no barriers,
//    fully independent 1-wave blocks.

typedef __attribute__((ext_vector_type(8))) short bf16x8;
typedef bf16x8 __attribute__((may_alias)) bf16x8_a;
typedef __attribute__((ext_vector_type(4))) float f32x4;
typedef __attribute__((ext_vector_type(2))) unsigned int u32x2;
typedef u32x2 __attribute__((may_alias)) u32x2_a;

__device__ inline unsigned short f2b(float f) {
  union { float f; unsigned int u; } x; x.f = f;
  unsigned int r = x.u + 0x7fffu + ((x.u >> 16) & 1u);  // RTNE
  return (unsigned short)(r >> 16);
}

__device__ inline unsigned cvtpk_bf16(float lo, float hi) {  // dst = {bf16(lo), bf16(hi)}
  unsigned r;
  asm("v_cvt_pk_bf16_f32 %0, %1, %2" : "=v"(r) : "v"(lo), "v"(hi));
  return r;
}

// One fused conversion kernel: blocks [0,4096) -> x, then 1024 blocks per weight.
__global__ __launch_bounds__(256) void cvt_all(
    const float* __restrict__ x,
    const float* __restrict__ w0, const float* __restrict__ w1,
    const float* __restrict__ w2, const float* __restrict__ w3,
    unsigned short* __restrict__ xb,
    unsigned short* __restrict__ o0, unsigned short* __restrict__ o1,
    unsigned short* __restrict__ o2, unsigned short* __restrict__ o3) {
  int bid = blockIdx.x;
  const float* in; unsigned short* out; int i;
  if (bid < 4096) { in = x; out = xb; i = bid * 256 + threadIdx.x; }
  else {
    int w = (bid - 4096) >> 10;
    in = (w == 0) ? w0 : (w == 1) ? w1 : (w == 2) ? w2 : w3;
    out = (w == 0) ? o0 : (w == 1) ? o1 : (w == 2) ? o2 : o3;
    i = ((bid - 4096) & 1023) * 256 + threadIdx.x;
  }
  float4 v = reinterpret_cast<const float4*>(in)[i];
  ushort4 o;
  o.x = f2b(v.x); o.y = f2b(v.y); o.z = f2b(v.z); o.w = f2b(v.w);
  reinterpret_cast<ushort4*>(out)[i] = o;
}

// C(MxN) = A(MxK) @ W(NxK)^T + bias.  128x128 tile, BK=64, 4 waves (each 64x64).
// 2-phase pipeline: dbuf LDS; per K-step {sync; stage(next->buf^1); compute(cur)}.
// MODE 0: z=0 -> Q bf16 row-major, pre-scaled by 0.125*log2e;
//         z=1 -> K bf16, kv'-permuted: addr = bh*131072 + kv'*64 + d.
// MODE 2: V, MFMA operands swapped so acc holds the TRANSPOSED tile; writes
//         VT'[bh][d][kv'] with lanes contiguous in kv' (coalesced 32B segments).
// MODE 1: fp32 output (final projection), row-major.
template<int MODE>
__global__ __launch_bounds__(256) void gemm_bt(
    const unsigned short* __restrict__ A,
    const unsigned short* __restrict__ W0, const unsigned short* __restrict__ W1,
    const float* __restrict__ b0, const float* __restrict__ b1,
    unsigned short* __restrict__ o0, unsigned short* __restrict__ o1,
    float* __restrict__ of, int M, int N, int K)
{
  const int tid = threadIdx.x;
  const int lane = tid & 63;
  const int wid = tid >> 6;
  const int q4 = lane >> 4;
  const int l15 = lane & 15;
  const int wr = wid >> 1, wc = wid & 1;

  const unsigned short* W = W0; const float* bias = b0; unsigned short* ob = o0;
  if (MODE == 0 && blockIdx.z == 1) { W = W1; bias = b1; ob = o1; }

  __shared__ __align__(16) unsigned short sA[2][128 * 64];
  __shared__ __align__(16) unsigned short sB[2][128 * 64];
  char* sAc = (char*)sA;
  char* sBc = (char*)sB;

  f32x4 acc[4][4];
#pragma unroll
  for (int i = 0; i < 4; ++i)
#pragma unroll
    for (int j = 0; j < 4; ++j) acc[i][j] = (f32x4){0.f, 0.f, 0.f, 0.f};

  const size_t rowA0 = (size_t)blockIdx.x * 128;
  const size_t rowB0 = (size_t)blockIdx.y * 128;

  auto stage = [&](int bs, int k0) {
#pragma unroll
    for (int it = 0; it < 4; ++it) {
      int Loff = it * 4096 + wid * 1024;          // wave-uniform LDS byte base
      int L = Loff + lane * 16;                   // linear LDS byte this lane fills
      int row = L >> 7;                           // tile row (128B per row)
      int csrc = ((L >> 4) & 7) ^ (row & 7);      // inverse-swizzled source chunk
      const unsigned short* ga = A + (rowA0 + row) * K + k0 + csrc * 8;
      const unsigned short* gw = W + (rowB0 + row) * K + k0 + csrc * 8;
      __builtin_amdgcn_global_load_lds((const __attribute__((address_space(1))) void*)ga,
                                       (__attribute__((address_space(3))) void*)(sAc + bs * 16384 + Loff),
                                       16, 0, 0);
      __builtin_amdgcn_global_load_lds((const __attribute__((address_space(1))) void*)gw,
                                       (__attribute__((address_space(3))) void*)(sBc + bs * 16384 + Loff),
                                       16, 0, 0);
    }
  };

  stage(0, 0);

  const int NT = K >> 6;
  for (int t = 0; t < NT; ++t) {
    const int cur = t & 1;
    __syncthreads();                 // drains tile t's loads; buf cur^1 reads done
    if (t + 1 < NT) stage(cur ^ 1, (t + 1) * 64);   // flies under compute(t)

#pragma unroll
    for (int ks = 0; ks < 2; ++ks) {
      bf16x8 af[4], bfr[4];
#pragma unroll
      for (int f = 0; f < 4; ++f) {
        int ra = wr * 64 + f * 16 + l15;
        af[f] = *(const bf16x8_a*)(sAc + cur * 16384 + ra * 128 +
                                   ((ks * 64 + q4 * 16) ^ ((ra & 7) << 4)));
        int rb = wc * 64 + f * 16 + l15;
        bfr[f] = *(const bf16x8_a*)(sBc + cur * 16384 + rb * 128 +
                                    ((ks * 64 + q4 * 16) ^ ((rb & 7) << 4)));
      }
      __builtin_amdgcn_s_setprio(1);
#pragma unroll
      for (int i = 0; i < 4; ++i)
#pragma unroll
        for (int j = 0; j < 4; ++j) {
          if (MODE == 2)
            acc[i][j] = __builtin_amdgcn_mfma_f32_16x16x32_bf16(bfr[j], af[i], acc[i][j], 0, 0, 0);
          else
            acc[i][j] = __builtin_amdgcn_mfma_f32_16x16x32_bf16(af[i], bfr[j], acc[i][j], 0, 0, 0);
        }
      __builtin_amdgcn_s_setprio(0);
    }
  }

  if (MODE == 2) {
    // acc[i][j][r] = value at (t = rowA0 + wr*64 + i*16 + l15,
    //                          c = rowB0 + wc*64 + j*16 + q4*4 + r)
    const int bh = (int)rowA0 >> 7;
#pragma unroll
    for (int i = 0; i < 4; ++i) {
      const int tt = wr * 64 + i * 16 + l15;       // within-head token, 0..127
      const size_t rb = (size_t)bh * 131072 + tt;
#pragma unroll
      for (int j = 0; j < 4; ++j) {
#pragma unroll
        for (int r = 0; r < 4; ++r) {
          const int c = (int)rowB0 + wc * 64 + j * 16 + q4 * 4 + r;
          ob[rb + (size_t)(c & 63) * 2048 + (size_t)(c >> 6) * 128] = f2b(acc[i][j][r] + bias[c]);
        }
      }
    }
  } else {
#pragma unroll
    for (int i = 0; i < 4; ++i) {
      int row = (int)rowA0 + wr * 64 + i * 16 + q4 * 4;
#pragma unroll
      for (int j = 0; j < 4; ++j) {
        int col = (int)rowB0 + wc * 64 + j * 16 + l15;
        float bv = bias[col];
        if (MODE == 0 && blockIdx.z == 1) {
          // K, kv'-permuted: addr = bh*131072 + ((col>>6)*128 + (row&127))*64 + d
#pragma unroll
          for (int r = 0; r < 4; ++r) {
            size_t a = (size_t)((row + r) >> 7) * 131072 +
                       (size_t)(((col >> 6) << 7) + ((row + r) & 127)) * 64 + (col & 63);
            ob[a] = f2b(acc[i][j][r] + bv);
          }
        } else {
#pragma unroll
          for (int r = 0; r < 4; ++r) {
            float v = acc[i][j][r] + bv;
            if (MODE == 0) ob[(size_t)(row + r) * N + col] = f2b(v * 0.18033688f);  // Q: 0.125*log2e
            else           of[(size_t)(row + r) * N + col] = v;
          }
        }
      }
    }
  }
}

// Flash attention, swapped-QK^T, ZERO-staging / ZERO-barrier version.
// 1 wave per block; wave owns 32 q-rows (2 subtiles of 16). All K/V MFMA
// fragments are contiguous 16B global loads served by the XCD-local L2
// (K'[kv][d] rows for A, VT[d][kv'] rows for B). Only P goes through LDS
// (wave-private, XOR-128 layout). Q pre-scaled => softmax in exp2 domain,
// defer-max (T13) skips the O-rescale when tile-max growth <= 11.54.
__global__ __launch_bounds__(64, 2) void attn_kernel(
    const unsigned short* __restrict__ Qg,
    const unsigned short* __restrict__ Kg,
    const unsigned short* __restrict__ VTg,
    unsigned short* __restrict__ ctx)
{
  const int lane = threadIdx.x;      // 1 wave per block
  const int q4 = lane >> 4;
  const int l15 = lane & 15;

  // XCD-aware decode: xcd = bid&7 owns 4 whole heads -> K/VT L2-resident.
  const int bid = blockIdx.x;        // 2048 blocks
  const int r = bid >> 3;            // 0..255
  const int bh = (bid & 7) * 4 + (r >> 6);
  const int qw = r & 63;             // 64 q-waves per head
  const int b = bh >> 4, h = bh & 15;
  const size_t base = (size_t)bh * 131072;
  const unsigned short* Qh = Qg + base;
  const unsigned short* Kh = Kg + base;
  const unsigned short* VTh = VTg + base;
  const int q0 = qw * 32;

  __shared__ __align__(16) unsigned short sP[32 * 64];   // wave-private P, XOR-128

  // Q fragments (B-operand of swapped QK^T): rows q0 + s*16 + l15
  bf16x8 qf[2][2];
#pragma unroll
  for (int s = 0; s < 2; ++s)
#pragma unroll
    for (int ks = 0; ks < 2; ++ks)
      qf[s][ks] = *(const bf16x8*)(Qh + (size_t)(q0 + s * 16 + l15) * 64 + ks * 32 + q4 * 8);

  // per-lane fragment base pointers (advance by tile inside the loop)
  const unsigned short* kbase = Kh + (size_t)(l15 * 64 + q4 * 8);          // + kv0*64 + fm*1024 + ks*32
  const unsigned short* vbase = VTh + (size_t)(l15 * 2048 + q4 * 8);       // + fn*32768 + kv0 + ks2*32
  char* sPc = (char*)sP;

  f32x4 oacc[2][4];                    // O[s][q=q4*4+r][d=fn*16+l15]
#pragma unroll
  for (int s = 0; s < 2; ++s)
#pragma unroll
    for (int fn = 0; fn < 4; ++fn) oacc[s][fn] = (f32x4){0.f, 0.f, 0.f, 0.f};
  float m_run[2] = {-INFINITY, -INFINITY};   // log2-domain state for q-row = l15
  float l_run[2] = {0.f, 0.f};

  for (int t = 0; t < 32; ++t) {
    const int kv0 = t * 64;

    // ---- load K fragments (A-operand) and V fragments (B-operand) from L2
    bf16x8 kf[2][4], vf[2][4];
#pragma unroll
    for (int ks = 0; ks < 2; ++ks)
#pragma unroll
      for (int fm = 0; fm < 4; ++fm)
        kf[ks][fm] = *(const bf16x8_a*)(kbase + (size_t)kv0 * 64 + fm * 1024 + ks * 32);
#pragma unroll
    for (int ks2 = 0; ks2 < 2; ++ks2)
#pragma unroll
      for (int fn = 0; fn < 4; ++fn)
        vf[ks2][fn] = *(const bf16x8_a*)(vbase + (size_t)fn * 32768 + kv0 + ks2 * 32);

    // ---- S^T = K Q^T : sc[s][fm][r] = S_log2[kv=fm*16+q4*4+r][q(s)=l15]
    f32x4 sc[2][4];
#pragma unroll
    for (int s = 0; s < 2; ++s)
#pragma unroll
      for (int fm = 0; fm < 4; ++fm) sc[s][fm] = (f32x4){0.f, 0.f, 0.f, 0.f};
    __builtin_amdgcn_s_setprio(1);
#pragma unroll
    for (int ks = 0; ks < 2; ++ks)
#pragma unroll
      for (int fm = 0; fm < 4; ++fm) {
        sc[0][fm] = __builtin_amdgcn_mfma_f32_16x16x32_bf16(kf[ks][fm], qf[0][ks], sc[0][fm], 0, 0, 0);
        sc[1][fm] = __builtin_amdgcn_mfma_f32_16x16x32_bf16(kf[ks][fm], qf[1][ks], sc[1][fm], 0, 0, 0);
      }
    __builtin_amdgcn_s_setprio(0);

    // ---- online softmax per subtile (exp2 domain, defer-max)
#pragma unroll
    for (int s = 0; s < 2; ++s) {
      float mx = fmaxf(fmaxf(fmaxf(sc[s][0][0], sc[s][0][1]), fmaxf(sc[s][0][2], sc[s][0][3])),
                       fmaxf(fmaxf(sc[s][1][0], sc[s][1][1]), fmaxf(sc[s][1][2], sc[s][1][3])));
      mx = fmaxf(mx, fmaxf(fmaxf(fmaxf(sc[s][2][0], sc[s][2][1]), fmaxf(sc[s][2][2], sc[s][2][3])),
                           fmaxf(fmaxf(sc[s][3][0], sc[s][3][1]), fmaxf(sc[s][3][2], sc[s][3][3]))));
      mx = fmaxf(mx, __shfl_xor(mx, 16));
      mx = fmaxf(mx, __shfl_xor(mx, 32));
      if (!__all(mx <= m_run[s] + 11.54f)) {   // wave-uniform rescale path
        const float mnew = fmaxf(m_run[s], mx);
        const float sc_o = __builtin_amdgcn_exp2f(m_run[s] - mnew);  // -inf on t=0 -> 0
        l_run[s] *= sc_o;
        m_run[s] = mnew;
#pragma unroll
        for (int rr = 0; rr < 4; ++rr) {
          const float so = __shfl(sc_o, (lane & 48) | (q4 * 4 + rr));
#pragma unroll
          for (int fn = 0; fn < 4; ++fn) oacc[s][fn][rr] *= so;
        }
      }
      float rs = 0.f;
#pragma unroll
      for (int fm = 0; fm < 4; ++fm)
#pragma unroll
        for (int rr = 0; rr < 4; ++rr) {
          sc[s][fm][rr] = __builtin_amdgcn_exp2f(sc[s][fm][rr] - m_run[s]);  // <= 2^11.54
          rs += sc[s][fm][rr];
        }
      rs += __shfl_xor(rs, 16);
      rs += __shfl_xor(rs, 32);
      l_run[s] += rs;

      // pack P -> sP[q=s*16+l15][kv], XOR-128 layout (kv = fm*16 + q4*4 + r)
      char* rowp = sPc + (s * 16 + l15) * 128;
#pragma unroll
      for (int fm = 0; fm < 4; ++fm) {
        u32x2 pk;
        pk[0] = cvtpk_bf16(sc[s][fm][0], sc[s][fm][1]);
        pk[1] = cvtpk_bf16(sc[s][fm][2], sc[s][fm][3]);
        *(u32x2_a*)(rowp + ((fm * 32 + q4 * 8) ^ ((l15 & 7) << 4))) = pk;
      }
    }
    // fence: cross-lane LDS exchange within the wave (writes above, reads below)
    asm volatile("s_waitcnt lgkmcnt(0)" ::: "memory");
    __builtin_amdgcn_sched_barrier(0);

    // ---- O += P V : A from sP (XOR-128), B = vf registers
#pragma unroll
    for (int ks2 = 0; ks2 < 2; ++ks2) {
      bf16x8 pf[2];
#pragma unroll
      for (int s = 0; s < 2; ++s)
        pf[s] = *(const bf16x8_a*)(sPc + (s * 16 + l15) * 128 +
                                   ((ks2 * 64 + q4 * 16) ^ ((l15 & 7) << 4)));
      __builtin_amdgcn_s_setprio(1);
#pragma unroll
      for (int fn = 0; fn < 4; ++fn) {
        oacc[0][fn] = __builtin_amdgcn_mfma_f32_16x16x32_bf16(pf[0], vf[ks2][fn], oacc[0][fn], 0, 0, 0);
        oacc[1][fn] = __builtin_amdgcn_mfma_f32_16x16x32_bf16(pf[1], vf[ks2][fn], oacc[1][fn], 0, 0, 0);
      }
      __builtin_amdgcn_s_setprio(0);
    }
  }

  // ---- normalize + store ctx[b, t, h*64+d]
#pragma unroll
  for (int s = 0; s < 2; ++s) {
    const float inv = 1.0f / l_run[s];
#pragma unroll
    for (int rr = 0; rr < 4; ++rr) {
      const float ir = __shfl(inv, (lane & 48) | (q4 * 4 + rr));
      const int trow = q0 + s * 16 + q4 * 4 + rr;
      const size_t ro = ((size_t)b * 2048 + trow) * 1024 + h * 64;
#pragma unroll
      for (int fn = 0; fn < 4; ++fn)
        ctx[ro + fn * 16 + l15] = f2b(oacc[s][fn][rr] * ir);
    }
  }
}

extern "C" void kernel_launch(void* const* d_in, const int* in_sizes, int n_in,
                              void* d_out, int out_size, void* d_ws, size_t ws_size,
                              hipStream_t stream) {
  const float* x  = (const float*)d_in[0];
  const float* wq = (const float*)d_in[1];
  const float* bq = (const float*)d_in[2];
  const float* wk = (const float*)d_in[3];
  const float* bk = (const float*)d_in[4];
  const float* wv = (const float*)d_in[5];
  const float* bv = (const float*)d_in[6];
  const float* wo = (const float*)d_in[7];
  const float* bo = (const float*)d_in[8];
  // d_in[9]/d_in[10] (rot tables) unused: constant-angle RoPE cancels in q.k^T.

  char* ws = (char*)d_ws;
  unsigned short* xb  = (unsigned short*)(ws);               // 8 MB (reused as ctx)
  unsigned short* wqb = (unsigned short*)(ws + 8388608);
  unsigned short* wkb = (unsigned short*)(ws + 10485760);
  unsigned short* wvb = (unsigned short*)(ws + 12582912);
  unsigned short* wob = (unsigned short*)(ws + 14680064);
  unsigned short* Qb  = (unsigned short*)(ws + 16777216);    // 8 MB
  unsigned short* Kb  = (unsigned short*)(ws + 25165824);    // 8 MB, kv'-permuted
  unsigned short* VTb = (unsigned short*)(ws + 33554432);    // 8 MB, [bh][d][kv']
  unsigned short* ctx = xb;  // x dead after QKV projection

  cvt_all<<<8192, 256, 0, stream>>>(x, wq, wk, wv, wo, xb, wqb, wkb, wvb, wob);

  gemm_bt<0><<<dim3(32, 8, 2), 256, 0, stream>>>(
      xb, wqb, wkb, bq, bk, Qb, Kb, nullptr, 4096, 1024, 1024);
  gemm_bt<2><<<dim3(32, 8, 1), 256, 0, stream>>>(
      xb, wvb, nullptr, bv, nullptr, VTb, nullptr, nullptr, 4096, 1024, 1024);

  attn_kernel<<<dim3(2048), dim3(64), 0, stream>>>(Qb, Kb, VTb, ctx);

  gemm_bt<1><<<dim3(32, 8, 1), 256, 0, stream>>>(
      ctx, wob, nullptr, bo, nullptr, nullptr, nullptr,
      (float*)d_out, 4096, 1024, 1024);
}

// Round 9
// 155.120 us; speedup vs baseline: 1.2534x; 1.2534x over previous
//
#include <hip/hip_runtime.h>
#include <hip/hip_bf16.h>
#include <stdint.h>

// MultiHeadSelfAttention (b=2,t=2048,m=1024,h=16,d=64), bf16 MFMA pipeline.
//  - reshape head-split => head h = contiguous 131072-elem slab of the per-batch
//    (2048x1024) projection; the [2048][64] view of the slab is token-ordered.
//  - constant-angle RoPE on q,k cancels exactly in q.k^T => skipped.
//  - K and V stored in a PERMUTED kv order kv' = (n>>6)*128 + (t&127); softmax/PV
//    are permutation-invariant when K and V share the ordering => coalesced VT write.
//  - Q pre-scaled by 0.125*log2(e) so attn softmax runs natively in exp2 domain.
//  - attn: K staged in LDS (block-shared, dbuf, barrier-pipelined); V fragments
//    loaded DIRECTLY global->reg (contiguous 16B VT rows), issued right after the
//    barrier so ~600cyc of QK^T+softmax hides their L2 latency (R8-verified addrs).

typedef __attribute__((ext_vector_type(8))) short bf16x8;
typedef bf16x8 __attribute__((may_alias)) bf16x8_a;
typedef __attribute__((ext_vector_type(4))) float f32x4;
typedef __attribute__((ext_vector_type(2))) unsigned int u32x2;
typedef u32x2 __attribute__((may_alias)) u32x2_a;

__device__ inline unsigned short f2b(float f) {
  union { float f; unsigned int u; } x; x.f = f;
  unsigned int r = x.u + 0x7fffu + ((x.u >> 16) & 1u);  // RTNE
  return (unsigned short)(r >> 16);
}

__device__ inline unsigned cvtpk_bf16(float lo, float hi) {  // dst = {bf16(lo), bf16(hi)}
  unsigned r;
  asm("v_cvt_pk_bf16_f32 %0, %1, %2" : "=v"(r) : "v"(lo), "v"(hi));
  return r;
}

// One fused conversion kernel: blocks [0,4096) -> x, then 1024 blocks per weight.
__global__ __launch_bounds__(256) void cvt_all(
    const float* __restrict__ x,
    const float* __restrict__ w0, const float* __restrict__ w1,
    const float* __restrict__ w2, const float* __restrict__ w3,
    unsigned short* __restrict__ xb,
    unsigned short* __restrict__ o0, unsigned short* __restrict__ o1,
    unsigned short* __restrict__ o2, unsigned short* __restrict__ o3) {
  int bid = blockIdx.x;
  const float* in; unsigned short* out; int i;
  if (bid < 4096) { in = x; out = xb; i = bid * 256 + threadIdx.x; }
  else {
    int w = (bid - 4096) >> 10;
    in = (w == 0) ? w0 : (w == 1) ? w1 : (w == 2) ? w2 : w3;
    out = (w == 0) ? o0 : (w == 1) ? o1 : (w == 2) ? o2 : o3;
    i = ((bid - 4096) & 1023) * 256 + threadIdx.x;
  }
  float4 v = reinterpret_cast<const float4*>(in)[i];
  ushort4 o;
  o.x = f2b(v.x); o.y = f2b(v.y); o.z = f2b(v.z); o.w = f2b(v.w);
  reinterpret_cast<ushort4*>(out)[i] = o;
}

// C(MxN) = A(MxK) @ W(NxK)^T + bias.  128x128 tile, BK=64, 4 waves (each 64x64).
// 2-phase pipeline: dbuf LDS; per K-step {sync; stage(next->buf^1); compute(cur)}.
// MODE 0: z=0 -> Q bf16 row-major, pre-scaled by 0.125*log2e;
//         z=1 -> K bf16, kv'-permuted: addr = bh*131072 + kv'*64 + d.
// MODE 2: V, MFMA operands swapped so acc holds the TRANSPOSED tile; writes
//         VT'[bh][d][kv'] with lanes contiguous in kv' (coalesced 32B segments).
// MODE 1: fp32 output (final projection), row-major.
template<int MODE>
__global__ __launch_bounds__(256) void gemm_bt(
    const unsigned short* __restrict__ A,
    const unsigned short* __restrict__ W0, const unsigned short* __restrict__ W1,
    const float* __restrict__ b0, const float* __restrict__ b1,
    unsigned short* __restrict__ o0, unsigned short* __restrict__ o1,
    float* __restrict__ of, int M, int N, int K)
{
  const int tid = threadIdx.x;
  const int lane = tid & 63;
  const int wid = tid >> 6;
  const int q4 = lane >> 4;
  const int l15 = lane & 15;
  const int wr = wid >> 1, wc = wid & 1;

  const unsigned short* W = W0; const float* bias = b0; unsigned short* ob = o0;
  if (MODE == 0 && blockIdx.z == 1) { W = W1; bias = b1; ob = o1; }

  __shared__ __align__(16) unsigned short sA[2][128 * 64];
  __shared__ __align__(16) unsigned short sB[2][128 * 64];
  char* sAc = (char*)sA;
  char* sBc = (char*)sB;

  f32x4 acc[4][4];
#pragma unroll
  for (int i = 0; i < 4; ++i)
#pragma unroll
    for (int j = 0; j < 4; ++j) acc[i][j] = (f32x4){0.f, 0.f, 0.f, 0.f};

  const size_t rowA0 = (size_t)blockIdx.x * 128;
  const size_t rowB0 = (size_t)blockIdx.y * 128;

  auto stage = [&](int bs, int k0) {
#pragma unroll
    for (int it = 0; it < 4; ++it) {
      int Loff = it * 4096 + wid * 1024;          // wave-uniform LDS byte base
      int L = Loff + lane * 16;                   // linear LDS byte this lane fills
      int row = L >> 7;                           // tile row (128B per row)
      int csrc = ((L >> 4) & 7) ^ (row & 7);      // inverse-swizzled source chunk
      const unsigned short* ga = A + (rowA0 + row) * K + k0 + csrc * 8;
      const unsigned short* gw = W + (rowB0 + row) * K + k0 + csrc * 8;
      __builtin_amdgcn_global_load_lds((const __attribute__((address_space(1))) void*)ga,
                                       (__attribute__((address_space(3))) void*)(sAc + bs * 16384 + Loff),
                                       16, 0, 0);
      __builtin_amdgcn_global_load_lds((const __attribute__((address_space(1))) void*)gw,
                                       (__attribute__((address_space(3))) void*)(sBc + bs * 16384 + Loff),
                                       16, 0, 0);
    }
  };

  stage(0, 0);

  const int NT = K >> 6;
  for (int t = 0; t < NT; ++t) {
    const int cur = t & 1;
    __syncthreads();                 // drains tile t's loads; buf cur^1 reads done
    if (t + 1 < NT) stage(cur ^ 1, (t + 1) * 64);   // flies under compute(t)

#pragma unroll
    for (int ks = 0; ks < 2; ++ks) {
      bf16x8 af[4], bfr[4];
#pragma unroll
      for (int f = 0; f < 4; ++f) {
        int ra = wr * 64 + f * 16 + l15;
        af[f] = *(const bf16x8_a*)(sAc + cur * 16384 + ra * 128 +
                                   ((ks * 64 + q4 * 16) ^ ((ra & 7) << 4)));
        int rb = wc * 64 + f * 16 + l15;
        bfr[f] = *(const bf16x8_a*)(sBc + cur * 16384 + rb * 128 +
                                    ((ks * 64 + q4 * 16) ^ ((rb & 7) << 4)));
      }
      __builtin_amdgcn_s_setprio(1);
#pragma unroll
      for (int i = 0; i < 4; ++i)
#pragma unroll
        for (int j = 0; j < 4; ++j) {
          if (MODE == 2)
            acc[i][j] = __builtin_amdgcn_mfma_f32_16x16x32_bf16(bfr[j], af[i], acc[i][j], 0, 0, 0);
          else
            acc[i][j] = __builtin_amdgcn_mfma_f32_16x16x32_bf16(af[i], bfr[j], acc[i][j], 0, 0, 0);
        }
      __builtin_amdgcn_s_setprio(0);
    }
  }

  if (MODE == 2) {
    // acc[i][j][r] = value at (t = rowA0 + wr*64 + i*16 + l15,
    //                          c = rowB0 + wc*64 + j*16 + q4*4 + r)
    const int bh = (int)rowA0 >> 7;
#pragma unroll
    for (int i = 0; i < 4; ++i) {
      const int tt = wr * 64 + i * 16 + l15;       // within-head token, 0..127
      const size_t rb = (size_t)bh * 131072 + tt;
#pragma unroll
      for (int j = 0; j < 4; ++j) {
#pragma unroll
        for (int r = 0; r < 4; ++r) {
          const int c = (int)rowB0 + wc * 64 + j * 16 + q4 * 4 + r;
          ob[rb + (size_t)(c & 63) * 2048 + (size_t)(c >> 6) * 128] = f2b(acc[i][j][r] + bias[c]);
        }
      }
    }
  } else {
#pragma unroll
    for (int i = 0; i < 4; ++i) {
      int row = (int)rowA0 + wr * 64 + i * 16 + q4 * 4;
#pragma unroll
      for (int j = 0; j < 4; ++j) {
        int col = (int)rowB0 + wc * 64 + j * 16 + l15;
        float bv = bias[col];
        if (MODE == 0 && blockIdx.z == 1) {
          // K, kv'-permuted: addr = bh*131072 + ((col>>6)*128 + (row&127))*64 + d
#pragma unroll
          for (int r = 0; r < 4; ++r) {
            size_t a = (size_t)((row + r) >> 7) * 131072 +
                       (size_t)(((col >> 6) << 7) + ((row + r) & 127)) * 64 + (col & 63);
            ob[a] = f2b(acc[i][j][r] + bv);
          }
        } else {
#pragma unroll
          for (int r = 0; r < 4; ++r) {
            float v = acc[i][j][r] + bv;
            if (MODE == 0) ob[(size_t)(row + r) * N + col] = f2b(v * 0.18033688f);  // Q: 0.125*log2e
            else           of[(size_t)(row + r) * N + col] = v;
          }
        }
      }
    }
  }
}

// Flash attention, swapped-QK^T. Q pre-scaled => S in log2 domain.
// Block = 256 thr (4 waves), 128 Q rows; each wave owns 32 q-rows (2 subtiles of
// 16) so every K LDS fragment read feeds 2 MFMAs. KV tiles of 64, dbuf K in LDS.
// V fragments load DIRECTLY global->reg, issued right after the barrier (hidden
// under QK^T + softmax). S^T = mfma(K,Q): lane(q4,l15) holds
// S[kv=fm*16+q4*4+r][q=l15] -> row softmax in 2 shfl_xor. Defer-max (T13).
// sP uses the GEMM-proven XOR-128 layout (conflict-free pfrag reads).
__global__ __launch_bounds__(256, 2) void attn_kernel(
    const unsigned short* __restrict__ Qg,
    const unsigned short* __restrict__ Kg,
    const unsigned short* __restrict__ VTg,
    unsigned short* __restrict__ ctx)
{
  const int tid = threadIdx.x;
  const int lane = tid & 63;
  const int wid = tid >> 6;          // 0..3
  const int q4 = lane >> 4;
  const int l15 = lane & 15;

  // XCD-aware decode: xcd = bid&7 owns 4 whole heads -> K/VT L2-resident.
  const int bid = blockIdx.x;
  const int bh = (bid & 7) * 4 + ((bid >> 3) >> 4);
  const int qt = (bid >> 3) & 15;
  const int b = bh >> 4, h = bh & 15;
  const size_t base = (size_t)bh * 131072;
  const unsigned short* Qh = Qg + base;
  const unsigned short* Kh = Kg + base;
  const unsigned short* VTh = VTg + base;
  const int q0 = qt * 128;

  __shared__ __align__(16) unsigned short sK[2][64 * 64];   // [kv'][d], XOR-swizzled
  __shared__ __align__(16) unsigned short sP[4][32 * 64];   // per-wave P[32 q][64 kv], XOR-128

  // Q fragments: subtile s rows = q0 + wid*32 + s*16 + l15
  bf16x8 qf[2][2];
#pragma unroll
  for (int s = 0; s < 2; ++s)
#pragma unroll
    for (int ks = 0; ks < 2; ++ks)
      qf[s][ks] = *(const bf16x8*)(Qh + (size_t)(q0 + wid * 32 + s * 16 + l15) * 64 + ks * 32 + q4 * 8);

  // K staging: 256 threads; each lane fills rows rr and rr+32
  const int rr = tid >> 3;                         // 0..31
  const int colB = ((tid & 7) ^ (rr & 7)) * 8;     // inverse of read-side XOR ((rr+32)&7 == rr&7)
  const unsigned short* gK = Kh + (size_t)rr * 64 + colB;      // + kv0*64
  // V fragments direct from global (R8-verified addressing):
  // vf[ks2][fn] = VT[d=fn*16+l15][kv0 + ks2*32 + q4*8 .. +7]
  const unsigned short* vbase = VTh + (size_t)l15 * 2048 + q4 * 8;
  char* sKc = (char*)sK;
  char* sPw = (char*)sP + wid * 4096;

  auto stageK = [&](int bs, int kv0) {
    __builtin_amdgcn_global_load_lds(
        (const __attribute__((address_space(1))) void*)(gK + (size_t)kv0 * 64),
        (__attribute__((address_space(3))) void*)(sKc + bs * 8192 + wid * 1024), 16, 0, 0);
    __builtin_amdgcn_global_load_lds(
        (const __attribute__((address_space(1))) void*)(gK + (size_t)kv0 * 64 + 2048),
        (__attribute__((address_space(3))) void*)(sKc + bs * 8192 + 4096 + wid * 1024), 16, 0, 0);
  };

  f32x4 oacc[2][4];                    // O[s][q=q4*4+r][d=fn*16+l15]
#pragma unroll
  for (int s = 0; s < 2; ++s)
#pragma unroll
    for (int fn = 0; fn < 4; ++fn) oacc[s][fn] = (f32x4){0.f, 0.f, 0.f, 0.f};
  float m_run[2] = {-INFINITY, -INFINITY};   // log2-domain state for q-row = l15
  float l_run[2] = {0.f, 0.f};

  stageK(0, 0);

  for (int t = 0; t < 32; ++t) {
    const int cur = t & 1;
    const int kv0 = t * 64;
    __syncthreads();                   // drains vmcnt: K(t) staged; buf cur^1 free
    if (t < 31) stageK(cur ^ 1, kv0 + 64);

    // ---- issue V(t) fragment loads NOW; consumed only after softmax (~600cyc)
    bf16x8 vf[2][4];
#pragma unroll
    for (int ks2 = 0; ks2 < 2; ++ks2)
#pragma unroll
      for (int fn = 0; fn < 4; ++fn)
        vf[ks2][fn] = *(const bf16x8_a*)(vbase + (size_t)fn * 32768 + kv0 + ks2 * 32);

    // ---- S^T = K Q^T : sc[s][fm][r] = S_log2[kv=fm*16+q4*4+r][q(s)=l15]
    f32x4 sc[2][4];
#pragma unroll
    for (int s = 0; s < 2; ++s)
#pragma unroll
      for (int fm = 0; fm < 4; ++fm) sc[s][fm] = (f32x4){0.f, 0.f, 0.f, 0.f};
    __builtin_amdgcn_s_setprio(1);
#pragma unroll
    for (int ks = 0; ks < 2; ++ks) {
#pragma unroll
      for (int fm = 0; fm < 4; ++fm) {
        const int rk = fm * 16 + l15;
        bf16x8_a kf = *(const bf16x8_a*)(sKc + cur * 8192 + rk * 128 +
                                         ((ks * 64 + q4 * 16) ^ ((rk & 7) << 4)));
        sc[0][fm] = __builtin_amdgcn_mfma_f32_16x16x32_bf16(kf, qf[0][ks], sc[0][fm], 0, 0, 0);
        sc[1][fm] = __builtin_amdgcn_mfma_f32_16x16x32_bf16(kf, qf[1][ks], sc[1][fm], 0, 0, 0);
      }
    }
    __builtin_amdgcn_s_setprio(0);

    // ---- online softmax per subtile (exp2 domain, defer-max)
#pragma unroll
    for (int s = 0; s < 2; ++s) {
      float mx = fmaxf(fmaxf(fmaxf(sc[s][0][0], sc[s][0][1]), fmaxf(sc[s][0][2], sc[s][0][3])),
                       fmaxf(fmaxf(sc[s][1][0], sc[s][1][1]), fmaxf(sc[s][1][2], sc[s][1][3])));
      mx = fmaxf(mx, fmaxf(fmaxf(fmaxf(sc[s][2][0], sc[s][2][1]), fmaxf(sc[s][2][2], sc[s][2][3])),
                           fmaxf(fmaxf(sc[s][3][0], sc[s][3][1]), fmaxf(sc[s][3][2], sc[s][3][3]))));
      mx = fmaxf(mx, __shfl_xor(mx, 16));
      mx = fmaxf(mx, __shfl_xor(mx, 32));
      if (!__all(mx <= m_run[s] + 11.54f)) {   // wave-uniform rescale path
        const float mnew = fmaxf(m_run[s], mx);
        const float sc_o = __builtin_amdgcn_exp2f(m_run[s] - mnew);  // -inf on t=0 -> 0
        l_run[s] *= sc_o;
        m_run[s] = mnew;
#pragma unroll
        for (int r = 0; r < 4; ++r) {
          const float so = __shfl(sc_o, (lane & 48) | (q4 * 4 + r));
#pragma unroll
          for (int fn = 0; fn < 4; ++fn) oacc[s][fn][r] *= so;
        }
      }
      float rs = 0.f;
#pragma unroll
      for (int fm = 0; fm < 4; ++fm)
#pragma unroll
        for (int r = 0; r < 4; ++r) {
          sc[s][fm][r] = __builtin_amdgcn_exp2f(sc[s][fm][r] - m_run[s]);  // <= 2^11.54
          rs += sc[s][fm][r];
        }
      rs += __shfl_xor(rs, 16);
      rs += __shfl_xor(rs, 32);
      l_run[s] += rs;

      // pack P -> sP[q=s*16+l15][kv], XOR-128 layout (kv = fm*16 + q4*4 + r)
      char* rowp = sPw + (s * 16 + l15) * 128;
#pragma unroll
      for (int fm = 0; fm < 4; ++fm) {
        u32x2 pk;
        pk[0] = cvtpk_bf16(sc[s][fm][0], sc[s][fm][1]);
        pk[1] = cvtpk_bf16(sc[s][fm][2], sc[s][fm][3]);
        *(u32x2_a*)(rowp + ((fm * 32 + q4 * 8) ^ ((l15 & 7) << 4))) = pk;
      }
    }
    // fence: cross-lane LDS exchange within the wave (writes above, reads below)
    asm volatile("s_waitcnt lgkmcnt(0)" ::: "memory");
    __builtin_amdgcn_sched_barrier(0);

    // ---- O += P V : A from sP (XOR-128), B = vf registers (already landed)
#pragma unroll
    for (int ks2 = 0; ks2 < 2; ++ks2) {
      bf16x8 pf[2];
#pragma unroll
      for (int s = 0; s < 2; ++s)
        pf[s] = *(const bf16x8_a*)(sPw + (s * 16 + l15) * 128 +
                                   ((ks2 * 64 + q4 * 16) ^ ((l15 & 7) << 4)));
      __builtin_amdgcn_s_setprio(1);
#pragma unroll
      for (int fn = 0; fn < 4; ++fn) {
        oacc[0][fn] = __builtin_amdgcn_mfma_f32_16x16x32_bf16(pf[0], vf[ks2][fn], oacc[0][fn], 0, 0, 0);
        oacc[1][fn] = __builtin_amdgcn_mfma_f32_16x16x32_bf16(pf[1], vf[ks2][fn], oacc[1][fn], 0, 0, 0);
      }
      __builtin_amdgcn_s_setprio(0);
    }
  }

  // ---- normalize + store ctx[b, t, h*64+d]
#pragma unroll
  for (int s = 0; s < 2; ++s) {
    const float inv = 1.0f / l_run[s];
#pragma unroll
    for (int r = 0; r < 4; ++r) {
      const float ir = __shfl(inv, (lane & 48) | (q4 * 4 + r));
      const int trow = q0 + wid * 32 + s * 16 + q4 * 4 + r;
      const size_t ro = ((size_t)b * 2048 + trow) * 1024 + h * 64;
#pragma unroll
      for (int fn = 0; fn < 4; ++fn)
        ctx[ro + fn * 16 + l15] = f2b(oacc[s][fn][r] * ir);
    }
  }
}

extern "C" void kernel_launch(void* const* d_in, const int* in_sizes, int n_in,
                              void* d_out, int out_size, void* d_ws, size_t ws_size,
                              hipStream_t stream) {
  const float* x  = (const float*)d_in[0];
  const float* wq = (const float*)d_in[1];
  const float* bq = (const float*)d_in[2];
  const float* wk = (const float*)d_in[3];
  const float* bk = (const float*)d_in[4];
  const float* wv = (const float*)d_in[5];
  const float* bv = (const float*)d_in[6];
  const float* wo = (const float*)d_in[7];
  const float* bo = (const float*)d_in[8];
  // d_in[9]/d_in[10] (rot tables) unused: constant-angle RoPE cancels in q.k^T.

  char* ws = (char*)d_ws;
  unsigned short* xb  = (unsigned short*)(ws);               // 8 MB (reused as ctx)
  unsigned short* wqb = (unsigned short*)(ws + 8388608);
  unsigned short* wkb = (unsigned short*)(ws + 10485760);
  unsigned short* wvb = (unsigned short*)(ws + 12582912);
  unsigned short* wob = (unsigned short*)(ws + 14680064);
  unsigned short* Qb  = (unsigned short*)(ws + 16777216);    // 8 MB
  unsigned short* Kb  = (unsigned short*)(ws + 25165824);    // 8 MB, kv'-permuted
  unsigned short* VTb = (unsigned short*)(ws + 33554432);    // 8 MB, [bh][d][kv']
  unsigned short* ctx = xb;  // x dead after QKV projection

  cvt_all<<<8192, 256, 0, stream>>>(x, wq, wk, wv, wo, xb, wqb, wkb, wvb, wob);

  gemm_bt<0><<<dim3(32, 8, 2), 256, 0, stream>>>(
      xb, wqb, wkb, bq, bk, Qb, Kb, nullptr, 4096, 1024, 1024);
  gemm_bt<2><<<dim3(32, 8, 1), 256, 0, stream>>>(
      xb, wvb, nullptr, bv, nullptr, VTb, nullptr, nullptr, 4096, 1024, 1024);

  attn_kernel<<<dim3(512), dim3(256), 0, stream>>>(Qb, Kb, VTb, ctx);

  gemm_bt<1><<<dim3(32, 8, 1), 256, 0, stream>>>(
      ctx, wob, nullptr, bo, nullptr, nullptr, nullptr,
      (float*)d_out, 4096, 1024, 1024);
}

// Round 10
// 132.647 us; speedup vs baseline: 1.4658x; 1.1694x over previous
//
#include <hip/hip_runtime.h>
#include <hip/hip_bf16.h>
#include <stdint.h>

// MultiHeadSelfAttention (b=2,t=2048,m=1024,h=16,d=64), bf16 MFMA pipeline.
//  - reshape head-split => head h = contiguous 131072-elem slab of the per-batch
//    (2048x1024) projection; the [2048][64] view of the slab is token-ordered.
//  - constant-angle RoPE on q,k cancels exactly in q.k^T => skipped.
//  - K and V stored in a PERMUTED kv order kv' = (n>>6)*128 + (t&127); softmax/PV
//    are permutation-invariant when K and V share the ordering => coalesced VT write.
//  - Q pre-scaled by 0.125*log2(e) so attn softmax runs natively in exp2 domain.
//  - attn: K and V staged in LDS via global_load_lds (R7-verified), KV-tile = 128
//    (2 x 64-kv subtiles per barrier) to halve barrier count.

typedef __attribute__((ext_vector_type(8))) short bf16x8;
typedef bf16x8 __attribute__((may_alias)) bf16x8_a;
typedef __attribute__((ext_vector_type(4))) float f32x4;
typedef __attribute__((ext_vector_type(2))) unsigned int u32x2;
typedef u32x2 __attribute__((may_alias)) u32x2_a;

__device__ inline unsigned short f2b(float f) {
  union { float f; unsigned int u; } x; x.f = f;
  unsigned int r = x.u + 0x7fffu + ((x.u >> 16) & 1u);  // RTNE
  return (unsigned short)(r >> 16);
}

__device__ inline unsigned cvtpk_bf16(float lo, float hi) {  // dst = {bf16(lo), bf16(hi)}
  unsigned r;
  asm("v_cvt_pk_bf16_f32 %0, %1, %2" : "=v"(r) : "v"(lo), "v"(hi));
  return r;
}

// One fused conversion kernel: blocks [0,4096) -> x, then 1024 blocks per weight.
__global__ __launch_bounds__(256) void cvt_all(
    const float* __restrict__ x,
    const float* __restrict__ w0, const float* __restrict__ w1,
    const float* __restrict__ w2, const float* __restrict__ w3,
    unsigned short* __restrict__ xb,
    unsigned short* __restrict__ o0, unsigned short* __restrict__ o1,
    unsigned short* __restrict__ o2, unsigned short* __restrict__ o3) {
  int bid = blockIdx.x;
  const float* in; unsigned short* out; int i;
  if (bid < 4096) { in = x; out = xb; i = bid * 256 + threadIdx.x; }
  else {
    int w = (bid - 4096) >> 10;
    in = (w == 0) ? w0 : (w == 1) ? w1 : (w == 2) ? w2 : w3;
    out = (w == 0) ? o0 : (w == 1) ? o1 : (w == 2) ? o2 : o3;
    i = ((bid - 4096) & 1023) * 256 + threadIdx.x;
  }
  float4 v = reinterpret_cast<const float4*>(in)[i];
  ushort4 o;
  o.x = f2b(v.x); o.y = f2b(v.y); o.z = f2b(v.z); o.w = f2b(v.w);
  reinterpret_cast<ushort4*>(out)[i] = o;
}

// C(MxN) = A(MxK) @ W(NxK)^T + bias.  128x128 tile, BK=64, 4 waves (each 64x64).
// 2-phase pipeline: dbuf LDS; per K-step {sync; stage(next->buf^1); compute(cur)}.
// MODE 0: z=0 -> Q bf16 row-major, pre-scaled by 0.125*log2e;
//         z=1 -> K bf16, kv'-permuted: addr = bh*131072 + kv'*64 + d.
// MODE 2: V, MFMA operands swapped so acc holds the TRANSPOSED tile; writes
//         VT'[bh][d][kv'] with lanes contiguous in kv' (coalesced 32B segments).
// MODE 1: fp32 output (final projection), row-major.
template<int MODE>
__global__ __launch_bounds__(256) void gemm_bt(
    const unsigned short* __restrict__ A,
    const unsigned short* __restrict__ W0, const unsigned short* __restrict__ W1,
    const float* __restrict__ b0, const float* __restrict__ b1,
    unsigned short* __restrict__ o0, unsigned short* __restrict__ o1,
    float* __restrict__ of, int M, int N, int K)
{
  const int tid = threadIdx.x;
  const int lane = tid & 63;
  const int wid = tid >> 6;
  const int q4 = lane >> 4;
  const int l15 = lane & 15;
  const int wr = wid >> 1, wc = wid & 1;

  const unsigned short* W = W0; const float* bias = b0; unsigned short* ob = o0;
  if (MODE == 0 && blockIdx.z == 1) { W = W1; bias = b1; ob = o1; }

  __shared__ __align__(16) unsigned short sA[2][128 * 64];
  __shared__ __align__(16) unsigned short sB[2][128 * 64];
  char* sAc = (char*)sA;
  char* sBc = (char*)sB;

  f32x4 acc[4][4];
#pragma unroll
  for (int i = 0; i < 4; ++i)
#pragma unroll
    for (int j = 0; j < 4; ++j) acc[i][j] = (f32x4){0.f, 0.f, 0.f, 0.f};

  const size_t rowA0 = (size_t)blockIdx.x * 128;
  const size_t rowB0 = (size_t)blockIdx.y * 128;

  auto stage = [&](int bs, int k0) {
#pragma unroll
    for (int it = 0; it < 4; ++it) {
      int Loff = it * 4096 + wid * 1024;          // wave-uniform LDS byte base
      int L = Loff + lane * 16;                   // linear LDS byte this lane fills
      int row = L >> 7;                           // tile row (128B per row)
      int csrc = ((L >> 4) & 7) ^ (row & 7);      // inverse-swizzled source chunk
      const unsigned short* ga = A + (rowA0 + row) * K + k0 + csrc * 8;
      const unsigned short* gw = W + (rowB0 + row) * K + k0 + csrc * 8;
      __builtin_amdgcn_global_load_lds((const __attribute__((address_space(1))) void*)ga,
                                       (__attribute__((address_space(3))) void*)(sAc + bs * 16384 + Loff),
                                       16, 0, 0);
      __builtin_amdgcn_global_load_lds((const __attribute__((address_space(1))) void*)gw,
                                       (__attribute__((address_space(3))) void*)(sBc + bs * 16384 + Loff),
                                       16, 0, 0);
    }
  };

  stage(0, 0);

  const int NT = K >> 6;
  for (int t = 0; t < NT; ++t) {
    const int cur = t & 1;
    __syncthreads();                 // drains tile t's loads; buf cur^1 reads done
    if (t + 1 < NT) stage(cur ^ 1, (t + 1) * 64);   // flies under compute(t)

#pragma unroll
    for (int ks = 0; ks < 2; ++ks) {
      bf16x8 af[4], bfr[4];
#pragma unroll
      for (int f = 0; f < 4; ++f) {
        int ra = wr * 64 + f * 16 + l15;
        af[f] = *(const bf16x8_a*)(sAc + cur * 16384 + ra * 128 +
                                   ((ks * 64 + q4 * 16) ^ ((ra & 7) << 4)));
        int rb = wc * 64 + f * 16 + l15;
        bfr[f] = *(const bf16x8_a*)(sBc + cur * 16384 + rb * 128 +
                                    ((ks * 64 + q4 * 16) ^ ((rb & 7) << 4)));
      }
      __builtin_amdgcn_s_setprio(1);
#pragma unroll
      for (int i = 0; i < 4; ++i)
#pragma unroll
        for (int j = 0; j < 4; ++j) {
          if (MODE == 2)
            acc[i][j] = __builtin_amdgcn_mfma_f32_16x16x32_bf16(bfr[j], af[i], acc[i][j], 0, 0, 0);
          else
            acc[i][j] = __builtin_amdgcn_mfma_f32_16x16x32_bf16(af[i], bfr[j], acc[i][j], 0, 0, 0);
        }
      __builtin_amdgcn_s_setprio(0);
    }
  }

  if (MODE == 2) {
    // acc[i][j][r] = value at (t = rowA0 + wr*64 + i*16 + l15,
    //                          c = rowB0 + wc*64 + j*16 + q4*4 + r)
    const int bh = (int)rowA0 >> 7;
#pragma unroll
    for (int i = 0; i < 4; ++i) {
      const int tt = wr * 64 + i * 16 + l15;       // within-head token, 0..127
      const size_t rb = (size_t)bh * 131072 + tt;
#pragma unroll
      for (int j = 0; j < 4; ++j) {
#pragma unroll
        for (int r = 0; r < 4; ++r) {
          const int c = (int)rowB0 + wc * 64 + j * 16 + q4 * 4 + r;
          ob[rb + (size_t)(c & 63) * 2048 + (size_t)(c >> 6) * 128] = f2b(acc[i][j][r] + bias[c]);
        }
      }
    }
  } else {
#pragma unroll
    for (int i = 0; i < 4; ++i) {
      int row = (int)rowA0 + wr * 64 + i * 16 + q4 * 4;
#pragma unroll
      for (int j = 0; j < 4; ++j) {
        int col = (int)rowB0 + wc * 64 + j * 16 + l15;
        float bv = bias[col];
        if (MODE == 0 && blockIdx.z == 1) {
          // K, kv'-permuted: addr = bh*131072 + ((col>>6)*128 + (row&127))*64 + d
#pragma unroll
          for (int r = 0; r < 4; ++r) {
            size_t a = (size_t)((row + r) >> 7) * 131072 +
                       (size_t)(((col >> 6) << 7) + ((row + r) & 127)) * 64 + (col & 63);
            ob[a] = f2b(acc[i][j][r] + bv);
          }
        } else {
#pragma unroll
          for (int r = 0; r < 4; ++r) {
            float v = acc[i][j][r] + bv;
            if (MODE == 0) ob[(size_t)(row + r) * N + col] = f2b(v * 0.18033688f);  // Q: 0.125*log2e
            else           of[(size_t)(row + r) * N + col] = v;
          }
        }
      }
    }
  }
}

// Flash attention, swapped-QK^T. Q pre-scaled => S in log2 domain.
// Block = 256 thr (4 waves), 128 Q rows; each wave owns 32 q-rows (2 subtiles of
// 16) so every K/V LDS fragment read feeds 2 MFMAs. KV tiles of 128 (2 x 64-kv
// subtiles per barrier -> 16 barriers instead of 32), dbuf K/VT in LDS.
// S^T = mfma(K,Q): lane(q4,l15) holds S[kv=fm*16+q4*4+r][q=l15] -> row softmax
// in 2 shfl_xor. Defer-max (T13). sP in XOR-128 layout (conflict-free reads).
__global__ __launch_bounds__(256, 2) void attn_kernel(
    const unsigned short* __restrict__ Qg,
    const unsigned short* __restrict__ Kg,
    const unsigned short* __restrict__ VTg,
    unsigned short* __restrict__ ctx)
{
  const int tid = threadIdx.x;
  const int lane = tid & 63;
  const int wid = tid >> 6;          // 0..3
  const int q4 = lane >> 4;
  const int l15 = lane & 15;

  // XCD-aware decode: xcd = bid&7 owns 4 whole heads -> K/VT L2-resident.
  const int bid = blockIdx.x;
  const int bh = (bid & 7) * 4 + ((bid >> 3) >> 4);
  const int qt = (bid >> 3) & 15;
  const int b = bh >> 4, h = bh & 15;
  const size_t base = (size_t)bh * 131072;
  const unsigned short* Qh = Qg + base;
  const unsigned short* Kh = Kg + base;
  const unsigned short* VTh = VTg + base;
  const int q0 = qt * 128;

  __shared__ __align__(16) unsigned short sK[2][128 * 64];  // 2 x (2 x [64kv][64d] subtile)
  __shared__ __align__(16) unsigned short sV[2][128 * 64];  // 2 x (2 x [64d][64kv] subtile)
  __shared__ __align__(16) unsigned short sP[4][32 * 64];   // per-wave P[32 q][64 kv], XOR-128

  // Q fragments: subtile s rows = q0 + wid*32 + s*16 + l15
  bf16x8 qf[2][2];
#pragma unroll
  for (int s = 0; s < 2; ++s)
#pragma unroll
    for (int ks = 0; ks < 2; ++ks)
      qf[s][ks] = *(const bf16x8*)(Qh + (size_t)(q0 + wid * 32 + s * 16 + l15) * 64 + ks * 32 + q4 * 8);

  // staging: 256 threads; each call fills 32 rows of a 64-row subtile
  const int rr = tid >> 3;                         // 0..31
  const int colB = ((tid & 7) ^ (rr & 7)) * 8;     // inverse of read-side XOR ((rr+32)&7 == rr&7)
  const unsigned short* gK = Kh + (size_t)rr * 64 + colB;      // + kv*64
  const unsigned short* gV = VTh + (size_t)rr * 2048 + colB;   // + kv
  char* sKc = (char*)sK;
  char* sVc = (char*)sV;
  char* sPw = (char*)sP + wid * 4096;

  // stage one 128-kv tile (two 64-kv subtiles) into buffer bs
  auto stage = [&](int bs, int kv0) {
#pragma unroll
    for (int hf = 0; hf < 2; ++hf) {
      const int kvh = kv0 + hf * 64;
      char* dK = sKc + bs * 16384 + hf * 8192 + wid * 1024;
      char* dV = sVc + bs * 16384 + hf * 8192 + wid * 1024;
      __builtin_amdgcn_global_load_lds(
          (const __attribute__((address_space(1))) void*)(gK + (size_t)kvh * 64),
          (__attribute__((address_space(3))) void*)dK, 16, 0, 0);
      __builtin_amdgcn_global_load_lds(
          (const __attribute__((address_space(1))) void*)(gK + (size_t)kvh * 64 + 2048),
          (__attribute__((address_space(3))) void*)(dK + 4096), 16, 0, 0);
      __builtin_amdgcn_global_load_lds(
          (const __attribute__((address_space(1))) void*)(gV + kvh),
          (__attribute__((address_space(3))) void*)dV, 16, 0, 0);
      __builtin_amdgcn_global_load_lds(
          (const __attribute__((address_space(1))) void*)(gV + kvh + 65536),
          (__attribute__((address_space(3))) void*)(dV + 4096), 16, 0, 0);
    }
  };

  f32x4 oacc[2][4];                    // O[s][q=q4*4+r][d=fn*16+l15]
#pragma unroll
  for (int s = 0; s < 2; ++s)
#pragma unroll
    for (int fn = 0; fn < 4; ++fn) oacc[s][fn] = (f32x4){0.f, 0.f, 0.f, 0.f};
  float m_run[2] = {-INFINITY, -INFINITY};   // log2-domain state for q-row = l15
  float l_run[2] = {0.f, 0.f};

  stage(0, 0);

  for (int t = 0; t < 16; ++t) {
    const int cur = t & 1;
    __syncthreads();                   // drains vmcnt: tile t staged; buf cur^1 free
    if (t < 15) stage(cur ^ 1, (t + 1) * 128);

#pragma unroll
    for (int hf = 0; hf < 2; ++hf) {
      const int bbase = cur * 16384 + hf * 8192;

      // ---- S^T = K Q^T : sc[s][fm][r] = S_log2[kv=fm*16+q4*4+r][q(s)=l15]
      f32x4 sc[2][4];
#pragma unroll
      for (int s = 0; s < 2; ++s)
#pragma unroll
        for (int fm = 0; fm < 4; ++fm) sc[s][fm] = (f32x4){0.f, 0.f, 0.f, 0.f};
      __builtin_amdgcn_s_setprio(1);
#pragma unroll
      for (int ks = 0; ks < 2; ++ks) {
#pragma unroll
        for (int fm = 0; fm < 4; ++fm) {
          const int rk = fm * 16 + l15;
          bf16x8_a kf = *(const bf16x8_a*)(sKc + bbase + rk * 128 +
                                           ((ks * 64 + q4 * 16) ^ ((rk & 7) << 4)));
          sc[0][fm] = __builtin_amdgcn_mfma_f32_16x16x32_bf16(kf, qf[0][ks], sc[0][fm], 0, 0, 0);
          sc[1][fm] = __builtin_amdgcn_mfma_f32_16x16x32_bf16(kf, qf[1][ks], sc[1][fm], 0, 0, 0);
        }
      }
      __builtin_amdgcn_s_setprio(0);

      // ---- online softmax per subtile (exp2 domain, defer-max)
#pragma unroll
      for (int s = 0; s < 2; ++s) {
        float mx = fmaxf(fmaxf(fmaxf(sc[s][0][0], sc[s][0][1]), fmaxf(sc[s][0][2], sc[s][0][3])),
                         fmaxf(fmaxf(sc[s][1][0], sc[s][1][1]), fmaxf(sc[s][1][2], sc[s][1][3])));
        mx = fmaxf(mx, fmaxf(fmaxf(fmaxf(sc[s][2][0], sc[s][2][1]), fmaxf(sc[s][2][2], sc[s][2][3])),
                             fmaxf(fmaxf(sc[s][3][0], sc[s][3][1]), fmaxf(sc[s][3][2], sc[s][3][3]))));
        mx = fmaxf(mx, __shfl_xor(mx, 16));
        mx = fmaxf(mx, __shfl_xor(mx, 32));
        if (!__all(mx <= m_run[s] + 11.54f)) {   // wave-uniform rescale path
          const float mnew = fmaxf(m_run[s], mx);
          const float sc_o = __builtin_amdgcn_exp2f(m_run[s] - mnew);  // -inf on t=0 -> 0
          l_run[s] *= sc_o;
          m_run[s] = mnew;
#pragma unroll
          for (int r = 0; r < 4; ++r) {
            const float so = __shfl(sc_o, (lane & 48) | (q4 * 4 + r));
#pragma unroll
            for (int fn = 0; fn < 4; ++fn) oacc[s][fn][r] *= so;
          }
        }
        float rs = 0.f;
#pragma unroll
        for (int fm = 0; fm < 4; ++fm)
#pragma unroll
          for (int r = 0; r < 4; ++r) {
            sc[s][fm][r] = __builtin_amdgcn_exp2f(sc[s][fm][r] - m_run[s]);  // <= 2^11.54
            rs += sc[s][fm][r];
          }
        rs += __shfl_xor(rs, 16);
        rs += __shfl_xor(rs, 32);
        l_run[s] += rs;

        // pack P -> sP[q=s*16+l15][kv], XOR-128 layout (kv = fm*16 + q4*4 + r)
        char* rowp = sPw + (s * 16 + l15) * 128;
#pragma unroll
        for (int fm = 0; fm < 4; ++fm) {
          u32x2 pk;
          pk[0] = cvtpk_bf16(sc[s][fm][0], sc[s][fm][1]);
          pk[1] = cvtpk_bf16(sc[s][fm][2], sc[s][fm][3]);
          *(u32x2_a*)(rowp + ((fm * 32 + q4 * 8) ^ ((l15 & 7) << 4))) = pk;
        }
      }
      // fence: cross-lane LDS exchange within the wave (writes above, reads below)
      asm volatile("s_waitcnt lgkmcnt(0)" ::: "memory");
      __builtin_amdgcn_sched_barrier(0);

      // ---- O += P V : A from sP (XOR-128), B = VT rows (d), same swizzle as K
#pragma unroll
      for (int ks2 = 0; ks2 < 2; ++ks2) {
        bf16x8 pf[2];
#pragma unroll
        for (int s = 0; s < 2; ++s)
          pf[s] = *(const bf16x8_a*)(sPw + (s * 16 + l15) * 128 +
                                     ((ks2 * 64 + q4 * 16) ^ ((l15 & 7) << 4)));
        __builtin_amdgcn_s_setprio(1);
#pragma unroll
        for (int fn = 0; fn < 4; ++fn) {
          const int rv = fn * 16 + l15;
          bf16x8_a vf = *(const bf16x8_a*)(sVc + bbase + rv * 128 +
                                           ((ks2 * 64 + q4 * 16) ^ ((rv & 7) << 4)));
          oacc[0][fn] = __builtin_amdgcn_mfma_f32_16x16x32_bf16(pf[0], vf, oacc[0][fn], 0, 0, 0);
          oacc[1][fn] = __builtin_amdgcn_mfma_f32_16x16x32_bf16(pf[1], vf, oacc[1][fn], 0, 0, 0);
        }
        __builtin_amdgcn_s_setprio(0);
      }
    }
  }

  // ---- normalize + store ctx[b, t, h*64+d]
#pragma unroll
  for (int s = 0; s < 2; ++s) {
    const float inv = 1.0f / l_run[s];
#pragma unroll
    for (int r = 0; r < 4; ++r) {
      const float ir = __shfl(inv, (lane & 48) | (q4 * 4 + r));
      const int trow = q0 + wid * 32 + s * 16 + q4 * 4 + r;
      const size_t ro = ((size_t)b * 2048 + trow) * 1024 + h * 64;
#pragma unroll
      for (int fn = 0; fn < 4; ++fn)
        ctx[ro + fn * 16 + l15] = f2b(oacc[s][fn][r] * ir);
    }
  }
}

extern "C" void kernel_launch(void* const* d_in, const int* in_sizes, int n_in,
                              void* d_out, int out_size, void* d_ws, size_t ws_size,
                              hipStream_t stream) {
  const float* x  = (const float*)d_in[0];
  const float* wq = (const float*)d_in[1];
  const float* bq = (const float*)d_in[2];
  const float* wk = (const float*)d_in[3];
  const float* bk = (const float*)d_in[4];
  const float* wv = (const float*)d_in[5];
  const float* bv = (const float*)d_in[6];
  const float* wo = (const float*)d_in[7];
  const float* bo = (const float*)d_in[8];
  // d_in[9]/d_in[10] (rot tables) unused: constant-angle RoPE cancels in q.k^T.

  char* ws = (char*)d_ws;
  unsigned short* xb  = (unsigned short*)(ws);               // 8 MB (reused as ctx)
  unsigned short* wqb = (unsigned short*)(ws + 8388608);
  unsigned short* wkb = (unsigned short*)(ws + 10485760);
  unsigned short* wvb = (unsigned short*)(ws + 12582912);
  unsigned short* wob = (unsigned short*)(ws + 14680064);
  unsigned short* Qb  = (unsigned short*)(ws + 16777216);    // 8 MB
  unsigned short* Kb  = (unsigned short*)(ws + 25165824);    // 8 MB, kv'-permuted
  unsigned short* VTb = (unsigned short*)(ws + 33554432);    // 8 MB, [bh][d][kv']
  unsigned short* ctx = xb;  // x dead after QKV projection

  cvt_all<<<8192, 256, 0, stream>>>(x, wq, wk, wv, wo, xb, wqb, wkb, wvb, wob);

  gemm_bt<0><<<dim3(32, 8, 2), 256, 0, stream>>>(
      xb, wqb, wkb, bq, bk, Qb, Kb, nullptr, 4096, 1024, 1024);
  gemm_bt<2><<<dim3(32, 8, 1), 256, 0, stream>>>(
      xb, wvb, nullptr, bv, nullptr, VTb, nullptr, nullptr, 4096, 1024, 1024);

  attn_kernel<<<dim3(512), dim3(256), 0, stream>>>(Qb, Kb, VTb, ctx);

  gemm_bt<1><<<dim3(32, 8, 1), 256, 0, stream>>>(
      ctx, wob, nullptr, bo, nullptr, nullptr, nullptr,
      (float*)d_out, 4096, 1024, 1024);
}